// Round 1
// baseline (130.186 us; speedup 1.0000x reference)
//
#include <hip/hip_runtime.h>
#include <hip/hip_bf16.h>

#define N_PTS 20000
#define NUM_CHUNKS 8
#define CAND_PER_CHUNK 2500   // 8 * 2500 = 20000
#define QBLK 256

// Kernel 1: per (query-block, candidate-chunk) partial argmin.
// partial[i*NUM_CHUNKS + ch] = (min_d2, bitcast(idx))
__global__ __launch_bounds__(QBLK) void nn_partial_kernel(
    const float* __restrict__ x,     // [N,3] queries
    const float* __restrict__ y,     // [N,3] candidates
    float2* __restrict__ partial) {
    __shared__ float sc[CAND_PER_CHUNK * 3];   // 30 KB

    const int qb = blockIdx.x;
    const int ch = blockIdx.y;
    const int cbase = ch * CAND_PER_CHUNK;

    // cooperative stage of the candidate chunk into LDS (coalesced)
    for (int t = threadIdx.x; t < CAND_PER_CHUNK * 3; t += QBLK)
        sc[t] = y[cbase * 3 + t];
    __syncthreads();

    const int i = qb * QBLK + (int)threadIdx.x;
    float qx = 0.f, qy = 0.f, qz = 0.f;
    if (i < N_PTS) {
        qx = x[i * 3 + 0];
        qy = x[i * 3 + 1];
        qz = x[i * 3 + 2];
    }

    float best = 3.4e38f;
    int bidx = cbase;

    // all 64 lanes read the same LDS address per j -> broadcast, conflict-free
    #pragma unroll 4
    for (int j = 0; j < CAND_PER_CHUNK; ++j) {
        const float dx = qx - sc[j * 3 + 0];
        const float dy = qy - sc[j * 3 + 1];
        const float dz = qz - sc[j * 3 + 2];
        const float d2 = fmaf(dx, dx, fmaf(dy, dy, dz * dz));
        if (d2 < best) { best = d2; bidx = cbase + j; }   // strict < keeps lowest idx
    }

    if (i < N_PTS)
        partial[i * NUM_CHUNKS + ch] = make_float2(best, __int_as_float(bidx));
}

// Kernel 2: reduce chunks per query (ascending chunk order, strict <),
// compare labels, count mismatches (one atomic per wave).
__global__ __launch_bounds__(QBLK) void nn_reduce_kernel(
    const float2* __restrict__ partial,
    const int* __restrict__ labels,
    unsigned int* __restrict__ count) {
    const int i = blockIdx.x * QBLK + (int)threadIdx.x;
    int mismatch = 0;
    if (i < N_PTS) {
        float best = 3.4e38f;
        int bidx = 0;
        #pragma unroll
        for (int c = 0; c < NUM_CHUNKS; ++c) {
            const float2 p = partial[i * NUM_CHUNKS + c];
            if (p.x < best) { best = p.x; bidx = __float_as_int(p.y); }
        }
        mismatch = (labels[bidx] != labels[i]) ? 1 : 0;
    }
    const unsigned long long m = __ballot(mismatch != 0);
    if ((threadIdx.x & 63) == 0)
        atomicAdd(count, (unsigned int)__popcll(m));
}

// Kernel 3: finalize scalar loss.
__global__ void nn_finalize_kernel(const unsigned int* __restrict__ count,
                                   float* __restrict__ out) {
    if (threadIdx.x == 0 && blockIdx.x == 0)
        out[0] = (float)count[0] / (float)N_PTS;
}

extern "C" void kernel_launch(void* const* d_in, const int* in_sizes, int n_in,
                              void* d_out, int out_size, void* d_ws, size_t ws_size,
                              hipStream_t stream) {
    const float* mean_3d      = (const float*)d_in[0];
    const float* mean_3d_cano = (const float*)d_in[1];
    const int*   segm_labels  = (const int*)d_in[2];
    float* out = (float*)d_out;

    // workspace layout
    float2* partial = (float2*)d_ws;                                  // 20000*8*8 = 1,280,000 B
    unsigned int* count = (unsigned int*)((char*)d_ws + 1310720);     // aligned past partials

    const int qblocks = (N_PTS + QBLK - 1) / QBLK;   // 79

    hipMemsetAsync(count, 0, sizeof(unsigned int), stream);

    dim3 grid1(qblocks, NUM_CHUNKS);
    nn_partial_kernel<<<grid1, QBLK, 0, stream>>>(mean_3d, mean_3d_cano, partial);
    nn_reduce_kernel<<<qblocks, QBLK, 0, stream>>>(partial, segm_labels, count);
    nn_finalize_kernel<<<1, 64, 0, stream>>>(count, out);
}

// Round 3
// 55.831 us; speedup vs baseline: 2.3318x; 2.3318x over previous
//
#include <hip/hip_runtime.h>

#define N_PTS 20000
#define NA 20480            // candidates padded to 640 tiles of 32
#define NB 20032            // queries padded to 313 wave-groups of 64
#define TILES_TOTAL 640

typedef __attribute__((ext_vector_type(8))) short bf16x8;
typedef __attribute__((ext_vector_type(16))) float f32x16;

static __device__ __forceinline__ unsigned short f2bf(float f) {
    unsigned int u = __float_as_uint(f);
    unsigned int r = (u + 0x7FFFu + ((u >> 16) & 1u)) >> 16;   // RNE
    return (unsigned short)r;
}
static __device__ __forceinline__ float bf2f(unsigned short h) {
    return __uint_as_float(((unsigned int)h) << 16);
}

// Build MFMA operand matrices.
// A row (candidate m), K=16 slots:
//   slots 0-2: -2*c_hi  (pairs with q_hi)
//   slots 3-5: -2*c_hi  (pairs with q_lo)
//   slots 6-8: -2*c_lo  (pairs with q_hi)
//   slots 9,10: y2 split hi/lo (pair with 1.0)
// => acc ~= ||y||^2 - 2 x.y  (key for argmin; x^2 constant per query)
__global__ __launch_bounds__(256) void nn_prep(const float* __restrict__ q,
                                               const float* __restrict__ c,
                                               unsigned short* __restrict__ Amat,
                                               unsigned short* __restrict__ Bmat) {
    const int m = blockIdx.x * 256 + (int)threadIdx.x;
    if (m < NA) {
        unsigned short a[16];
        #pragma unroll
        for (int r = 0; r < 16; ++r) a[r] = 0;
        if (m < N_PTS) {
            const float cx = c[m * 3 + 0], cy = c[m * 3 + 1], cz = c[m * 3 + 2];
            const unsigned short hx = f2bf(cx), hy = f2bf(cy), hz = f2bf(cz);
            const float lx = cx - bf2f(hx), ly = cy - bf2f(hy), lz = cz - bf2f(hz);
            const float y2 = fmaf(cx, cx, fmaf(cy, cy, cz * cz));
            const unsigned short y2h = f2bf(y2);
            const unsigned short y2l = f2bf(y2 - bf2f(y2h));
            a[0] = f2bf(-2.f * bf2f(hx)); a[1] = f2bf(-2.f * bf2f(hy)); a[2] = f2bf(-2.f * bf2f(hz));
            a[3] = a[0]; a[4] = a[1]; a[5] = a[2];
            a[6] = f2bf(-2.f * lx); a[7] = f2bf(-2.f * ly); a[8] = f2bf(-2.f * lz);
            a[9] = y2h; a[10] = y2l;
        } else {
            a[9] = f2bf(1e30f);   // padded candidates: huge key, never wins
        }
        unsigned int* o = (unsigned int*)(Amat + (size_t)m * 16);
        #pragma unroll
        for (int r = 0; r < 8; ++r)
            o[r] = (unsigned int)a[2 * r] | ((unsigned int)a[2 * r + 1] << 16);
    }
    if (m < NB) {
        unsigned short b[16];
        #pragma unroll
        for (int r = 0; r < 16; ++r) b[r] = 0;
        if (m < N_PTS) {
            const float qx = q[m * 3 + 0], qy = q[m * 3 + 1], qz = q[m * 3 + 2];
            const unsigned short hx = f2bf(qx), hy = f2bf(qy), hz = f2bf(qz);
            b[0] = hx; b[1] = hy; b[2] = hz;
            b[3] = f2bf(qx - bf2f(hx)); b[4] = f2bf(qy - bf2f(hy)); b[5] = f2bf(qz - bf2f(hz));
            b[6] = hx; b[7] = hy; b[8] = hz;
            b[9] = f2bf(1.0f); b[10] = f2bf(1.0f);
        }
        unsigned int* o = (unsigned int*)(Bmat + (size_t)m * 16);
        #pragma unroll
        for (int r = 0; r < 8; ++r)
            o[r] = (unsigned int)b[2 * r] | ((unsigned int)b[2 * r + 1] << 16);
    }
}

// Min over a tile's 16 acc regs with the reg index packed into mantissa low 4 bits.
static __device__ __forceinline__ float tile_min16(const f32x16& acc) {
    float v[16];
    #pragma unroll
    for (int r = 0; r < 16; ++r)
        v[r] = __uint_as_float((__float_as_uint(acc[r]) & 0xFFFFFFF0u) | (unsigned)r);
    const float a = fminf(fminf(v[0], v[1]), v[2]);
    const float b = fminf(fminf(v[3], v[4]), v[5]);
    const float c = fminf(fminf(v[6], v[7]), v[8]);
    const float d = fminf(fminf(v[9], v[10]), v[11]);
    const float e = fminf(fminf(v[12], v[13]), v[14]);
    const float f = fminf(fminf(a, b), c);
    const float g = fminf(fminf(d, e), v[15]);
    return fminf(f, g);
}

// Each wave: 64 queries (2 B-frags) x one candidate chunk of tpc tiles.
// C/D layout (m74/m101): col=lane&31 (query), row=(reg&3)+8*(reg>>2)+4*(lane>>5) (candidate)
__global__ __launch_bounds__(256) void nn_main(const unsigned short* __restrict__ Amat,
                                               const unsigned short* __restrict__ Bmat,
                                               float2* __restrict__ partial,
                                               int lc) {
    const int C = 1 << lc;
    const int tpc = TILES_TOTAL >> lc;
    const int wid = blockIdx.x * 4 + (int)(threadIdx.x >> 6);
    const int nw = 313 << lc;
    if (wid >= nw) return;
    const int lane = (int)(threadIdx.x & 63);
    const int qg = wid >> lc;
    const int ch = wid & (C - 1);
    const int qbase = qg * 64;
    const int lane31 = lane & 31;
    const int half = lane >> 5;

    const bf16x8 b1 = *(const bf16x8*)(Bmat + (size_t)(qbase + lane31) * 16 + half * 8);
    const bf16x8 b2 = *(const bf16x8*)(Bmat + (size_t)(qbase + 32 + lane31) * 16 + half * 8);

    const f32x16 zacc = {0.f, 0.f, 0.f, 0.f, 0.f, 0.f, 0.f, 0.f,
                         0.f, 0.f, 0.f, 0.f, 0.f, 0.f, 0.f, 0.f};

    float best1 = __uint_as_float(0x7F800000u), best2 = best1;   // +inf
    int bt1 = 0, bt2 = 0;

    const int t0 = ch * tpc;
    for (int t = 0; t < tpc; ++t) {
        const int tile = t0 + t;
        const bf16x8 af = *(const bf16x8*)(Amat + (size_t)(tile * 32 + lane31) * 16 + half * 8);
        const f32x16 acc1 = __builtin_amdgcn_mfma_f32_32x32x16_bf16(af, b1, zacc, 0, 0, 0);
        const f32x16 acc2 = __builtin_amdgcn_mfma_f32_32x32x16_bf16(af, b2, zacc, 0, 0, 0);
        const float t1 = tile_min16(acc1);
        if (t1 < best1) { best1 = t1; bt1 = tile; }
        const float t2 = tile_min16(acc2);
        if (t2 < best2) { best2 = t2; bt2 = tile; }
    }

    // recover candidate index, then merge the two row-halves (lane ^ 32)
    unsigned slot1 = __float_as_uint(best1) & 15u;
    int idx1 = bt1 * 32 + (int)(slot1 & 3u) + 8 * (int)(slot1 >> 2) + 4 * half;
    unsigned slot2 = __float_as_uint(best2) & 15u;
    int idx2 = bt2 * 32 + (int)(slot2 & 3u) + 8 * (int)(slot2 >> 2) + 4 * half;

    const float ob1 = __shfl_xor(best1, 32);
    const int oi1 = __shfl_xor(idx1, 32);
    if (ob1 < best1 || (ob1 == best1 && oi1 < idx1)) { best1 = ob1; idx1 = oi1; }
    const float ob2 = __shfl_xor(best2, 32);
    const int oi2 = __shfl_xor(idx2, 32);
    if (ob2 < best2 || (ob2 == best2 && oi2 < idx2)) { best2 = ob2; idx2 = oi2; }

    if (lane < 32) {
        const int q1 = qbase + lane;
        if (q1 < N_PTS) partial[(size_t)q1 * C + ch] = make_float2(best1, __int_as_float(idx1));
        const int q2 = qbase + 32 + lane;
        if (q2 < N_PTS) partial[(size_t)q2 * C + ch] = make_float2(best2, __int_as_float(idx2));
    }
}

__global__ __launch_bounds__(256) void nn_reduce(const float2* __restrict__ partial,
                                                 const int* __restrict__ labels,
                                                 unsigned int* __restrict__ count, int C) {
    const int i = blockIdx.x * 256 + (int)threadIdx.x;
    int mism = 0;
    if (i < N_PTS) {
        float best = __uint_as_float(0x7F800000u);
        int bidx = 0;
        for (int c = 0; c < C; ++c) {                       // ascending chunk, strict <
            const float2 p = partial[(size_t)i * C + c];
            if (p.x < best) { best = p.x; bidx = __float_as_int(p.y); }
        }
        mism = (labels[bidx] != labels[i]) ? 1 : 0;
    }
    const unsigned long long msk = __ballot(mism != 0);
    if ((threadIdx.x & 63) == 0) atomicAdd(count, (unsigned)__popcll(msk));
}

__global__ void nn_finalize(const unsigned int* __restrict__ count, float* __restrict__ out) {
    if (threadIdx.x == 0 && blockIdx.x == 0)
        out[0] = (float)count[0] / (float)N_PTS;
}

extern "C" void kernel_launch(void* const* d_in, const int* in_sizes, int n_in,
                              void* d_out, int out_size, void* d_ws, size_t ws_size,
                              hipStream_t stream) {
    const float* mean_3d      = (const float*)d_in[0];
    const float* mean_3d_cano = (const float*)d_in[1];
    const int*   segm_labels  = (const int*)d_in[2];
    float* out = (float*)d_out;

    unsigned short* Amat = (unsigned short*)d_ws;                         // 655,360 B
    unsigned short* Bmat = (unsigned short*)((char*)d_ws + 655360);       // 641,024 B
    float2* partial = (float2*)((char*)d_ws + 1310720);

    int lc = 4;                                                           // 16 chunks if ws allows
    while (lc > 0 && 1310720ull + 20000ull * (1ull << lc) * 8ull + 4ull > ws_size) --lc;
    const int C = 1 << lc;
    unsigned int* count = (unsigned int*)((char*)d_ws + 1310720 + 20000ull * (size_t)C * 8ull);

    (void)hipMemsetAsync(count, 0, sizeof(unsigned int), stream);
    nn_prep<<<NA / 256, 256, 0, stream>>>(mean_3d, mean_3d_cano, Amat, Bmat);
    const int nw = 313 * C;
    nn_main<<<(nw + 3) / 4, 256, 0, stream>>>(Amat, Bmat, partial, lc);
    nn_reduce<<<(N_PTS + 255) / 256, 256, 0, stream>>>(partial, segm_labels, count, C);
    nn_finalize<<<1, 64, 0, stream>>>(count, out);
}